// Round 10
// baseline (214.891 us; speedup 1.0000x reference)
//
#include <hip/hip_runtime.h>
#include <hip/hip_bf16.h>
#include <math.h>

typedef unsigned short ushort_t;
typedef unsigned int   uint_t;
typedef __attribute__((ext_vector_type(8))) short  bf16x8;
typedef __attribute__((ext_vector_type(4))) float  f32x4;
typedef __attribute__((ext_vector_type(4))) int    int4v;
typedef __attribute__((ext_vector_type(2))) int    i32x2;
typedef __attribute__((ext_vector_type(4))) short  s16x4;

#define MFMA16(a, b, c) __builtin_amdgcn_mfma_f32_16x16x32_bf16((a), (b), (c), 0, 0, 0)

static constexpr int BATCH = 2;
static constexpr int SEQ   = 2048;
static constexpr int DMODEL = 512;
static constexpr int NHEADS = 8;
static constexpr int DK    = 64;
static constexpr int MROWS = BATCH * SEQ;          // 4096
static constexpr int XE = MROWS * DMODEL;          // 2097152 elems
static constexpr int WE = DMODEL * DMODEL;         // 262144 elems
static constexpr int NQKV = 3 * DMODEL;            // 1536 fused-projection cols
static constexpr int NSPLIT = 4;                   // split-K factor for attention
static constexpr int KB_PER = (SEQ / 64) / NSPLIT; // 8 k-blocks per split

// 0.125 (1/sqrt(DK)) * log2(e): folded into Wq/bq so softmax runs in log2 domain
static constexpr float QSCALE_L2E = 0.18033688011112043f;
static constexpr float L2E = 1.4426950408889634f;

__device__ __forceinline__ ushort_t f2bf(float f) {
  unsigned int u = __builtin_bit_cast(unsigned int, f);
  u = (u + 0x7FFFu + ((u >> 16) & 1u)) >> 16;
  return (ushort_t)u;
}

// 2^x via v_exp_f32 (no pre-multiply)
__device__ __forceinline__ float fexp2(float x) {
  float r;
  asm("v_exp_f32 %0, %1" : "=v"(r) : "v"(x));
  return r;
}

// pack 2 f32 -> 2 bf16 (RNE), lo <- a, hi <- b
__device__ __forceinline__ int cvt_pk_bf16(float a, float b) {
  int r;
  asm("v_cvt_pk_bf16_f32 %0, %1, %2" : "=v"(r) : "v"(a), "v"(b));
  return r;
}

// max across the 16 lanes of a DPP row (lanes 0-15 / 16-31 / ...), pure VALU
__device__ __forceinline__ float rowmax16(float x) {
  int t;
  t = __builtin_amdgcn_mov_dpp(__builtin_bit_cast(int, x), 0xB1, 0xF, 0xF, true);   // quad_perm [1,0,3,2]
  x = fmaxf(x, __builtin_bit_cast(float, t));
  t = __builtin_amdgcn_mov_dpp(__builtin_bit_cast(int, x), 0x4E, 0xF, 0xF, true);   // quad_perm [2,3,0,1]
  x = fmaxf(x, __builtin_bit_cast(float, t));
  t = __builtin_amdgcn_mov_dpp(__builtin_bit_cast(int, x), 0x141, 0xF, 0xF, true);  // row_half_mirror (xor4)
  x = fmaxf(x, __builtin_bit_cast(float, t));
  t = __builtin_amdgcn_mov_dpp(__builtin_bit_cast(int, x), 0x140, 0xF, 0xF, true);  // row_mirror (xor8)
  x = fmaxf(x, __builtin_bit_cast(float, t));
  return x;
}

// async 16B/lane global -> LDS (lands at lds_base + lane*16)
__device__ __forceinline__ void async16(const ushort_t* g, ushort_t* l) {
  __builtin_amdgcn_global_load_lds(
      (const __attribute__((address_space(1))) unsigned int*)g,
      (__attribute__((address_space(3))) unsigned int*)l, 16, 0, 0);
}

// ---------------------------------------------------------------------------
// 1) Fused prep kernel (ONE launch):
//    - fp32 -> bf16 convert of x, Wq, Wk, Wv, Wo (Wq/bq pre-scaled by
//      0.125*log2e -> log2-domain softmax)
//    - bias concat block
//    - D,A fp32 -> interleaved bf16 pack (lo16 = D, hi16 = A)
// ---------------------------------------------------------------------------
static constexpr int CONV_BLOCKS = (XE + 4 * WE) / 1024;          // 2560
static constexpr int PACK_BLOCKS = (BATCH * SEQ * SEQ) / 1024;    // 8192

__global__ __launch_bounds__(256) void convert_pack_kernel(
    const float* __restrict__ x,  const float* __restrict__ wq,
    const float* __restrict__ wk, const float* __restrict__ wv,
    const float* __restrict__ wo,
    const float* __restrict__ bq, const float* __restrict__ bk,
    const float* __restrict__ bv,
    const float* __restrict__ Dm, const float* __restrict__ Am,
    ushort_t* __restrict__ dst, float* __restrict__ bqkv,
    uint_t* __restrict__ DAb) {
  const int bid = blockIdx.x;
  if (bid == CONV_BLOCKS) {  // bias-concat block
    for (int i = threadIdx.x; i < NQKV; i += 256) {
      bqkv[i] = (i < 512) ? bq[i] * QSCALE_L2E
              : (i < 1024) ? bk[i - 512] : bv[i - 1024];
    }
    return;
  }
  if (bid > CONV_BLOCKS) {  // D/A pack blocks
    int e = ((bid - CONV_BLOCKS - 1) * 256 + threadIdx.x) * 4;
    float4 d = *reinterpret_cast<const float4*>(&Dm[e]);
    float4 a = *reinterpret_cast<const float4*>(&Am[e]);
    int4v v;
    v[0] = (int)((uint_t)f2bf(d.x) | ((uint_t)f2bf(a.x) << 16));
    v[1] = (int)((uint_t)f2bf(d.y) | ((uint_t)f2bf(a.y) << 16));
    v[2] = (int)((uint_t)f2bf(d.z) | ((uint_t)f2bf(a.z) << 16));
    v[3] = (int)((uint_t)f2bf(d.w) | ((uint_t)f2bf(a.w) << 16));
    *reinterpret_cast<int4v*>(&DAb[e]) = v;
    return;
  }
  int e = (bid * 256 + threadIdx.x) * 4;
  const float* src;
  int off;
  float qs = 1.0f;
  if (e < XE)                { src = x;  off = e; }
  else if (e < XE + WE)      { src = wq; off = e - XE; qs = QSCALE_L2E; }
  else if (e < XE + 2 * WE)  { src = wk; off = e - XE - WE; }
  else if (e < XE + 3 * WE)  { src = wv; off = e - XE - 2 * WE; }
  else                       { src = wo; off = e - XE - 3 * WE; }
  float4 f = *reinterpret_cast<const float4*>(&src[off]);
  s16x4 v;
  v[0] = (short)f2bf(f.x * qs); v[1] = (short)f2bf(f.y * qs);
  v[2] = (short)f2bf(f.z * qs); v[3] = (short)f2bf(f.w * qs);
  *reinterpret_cast<s16x4*>(&dst[e]) = v;
}

// ---------------------------------------------------------------------------
// 2a) bf16 GEMM, 128x64 tile / WG (4 waves, each owning a 64x32 quadrant).
//     Used for the QKV projection (grid 24x32 = 768 WGs = 3/CU).
//     T1 XCD-aware block remap. XOR-swizzle invariant:
//     LDS[r][slot*8+j] holds global col-block (slot ^ (r&7)) of the k-tile;
//     fragment read at col 8*((blk) ^ (l15&7)).
// ---------------------------------------------------------------------------
template <bool F32OUT>
__global__ __launch_bounds__(256) void gemm_bt128x64(
    const ushort_t* __restrict__ A, const ushort_t* __restrict__ Bt,
    const float* __restrict__ bias, void* __restrict__ C,
    int N, int K) {
  __shared__ ushort_t As[128][64];
  __shared__ ushort_t Bs[64][64];
  const int tid  = threadIdx.x;
  const int wave = tid >> 6, lane = tid & 63;
  const int quad = lane >> 4, l15 = lane & 15;

  // T1 XCD-aware remap (grid sizes are multiples of 8)
  const int nb  = blockIdx.x + blockIdx.y * gridDim.x;
  const int tot = gridDim.x * gridDim.y;
  const int w   = (nb & 7) * (tot >> 3) + (nb >> 3);
  const int bx  = w % gridDim.x, by = w / gridDim.x;
  const int m0 = by * 128, n0 = bx * 64;
  const int wr = (wave >> 1) * 64, wc = (wave & 1) * 32;  // wave's C quadrant

  f32x4 acc[4][2] = {};

  // staging: A 128 rows (4 x async16/wave), B 64 rows (2 x async16/wave)
  const int lrow = lane >> 3, slot = lane & 7;
  const int cswz = 8 * (slot ^ lrow);
  const ushort_t* ag = A  + (size_t)(m0 + wave * 8 + lrow) * K + cswz;
  const ushort_t* bg = Bt + (size_t)(n0 + wave * 16 + lrow) * K + cswz;
  ushort_t* la[4];
#pragma unroll
  for (int r0 = 0; r0 < 4; r0++) la[r0] = &As[r0 * 32 + wave * 8][0];
  ushort_t* lb0 = &Bs[wave * 16][0];
  ushort_t* lb1 = &Bs[wave * 16 + 8][0];

  const int swz = l15 & 7;

  for (int k0 = 0; k0 < K; k0 += 64) {
    __syncthreads();
#pragma unroll
    for (int r0 = 0; r0 < 4; r0++)
      async16(ag + k0 + (size_t)(r0 * 32) * K, la[r0]);
    async16(bg + k0, lb0);
    async16(bg + k0 + 8 * (size_t)K, lb1);
    asm volatile("s_waitcnt vmcnt(0)" ::: "memory");
    __syncthreads();
#pragma unroll
    for (int s = 0; s < 2; s++) {
      const int acol = 8 * ((s * 4 + quad) ^ swz);
      bf16x8 af[4], bfr[2];
#pragma unroll
      for (int i = 0; i < 4; i++)
        af[i] = *reinterpret_cast<const bf16x8*>(&As[wr + i * 16 + l15][acol]);
#pragma unroll
      for (int j = 0; j < 2; j++)
        bfr[j] = *reinterpret_cast<const bf16x8*>(&Bs[wc + j * 16 + l15][acol]);
#pragma unroll
      for (int i = 0; i < 4; i++)
#pragma unroll
        for (int j = 0; j < 2; j++)
          acc[i][j] = MFMA16(af[i], bfr[j], acc[i][j]);
    }
  }

#pragma unroll
  for (int j = 0; j < 2; j++) {
    const int col = n0 + wc + j * 16 + l15;
    const float bv = bias[col];
#pragma unroll
    for (int i = 0; i < 4; i++) {
#pragma unroll
      for (int rr = 0; rr < 4; rr++) {
        const int row = m0 + wr + i * 16 + quad * 4 + rr;
        const float v = acc[i][j][rr] + bv;
        if (F32OUT) reinterpret_cast<float*>(C)[(size_t)row * N + col] = v;
        else        reinterpret_cast<ushort_t*>(C)[(size_t)row * N + col] = f2bf(v);
      }
    }
  }
}

// ---------------------------------------------------------------------------
// 2b) FUSED split-K combine + O-projection GEMM, 64x64 tile / WG.
//     Key alignment facts: each 64-wide K-tile of the O-GEMM == one head h
//     (k0>>6), and each 64-row A-tile == one (b, qb) block. So the A-tile for
//     K-tile k0 is exactly combine(Opart[b, h, qb, s=0..3]) -- computed here
//     in-staging (float4 loads -> w_s-weighted sum * 1/L -> cvt_pk bf16 ->
//     ds_write_b128 into the SAME XOR-swizzle layout: block cb at LDS col
//     8*(cb ^ (r&7))). Eliminates the combine kernel + AO round-trip.
//     B (Wo) staging via async16 unchanged; MFMA loop identical to gemm_bt64.
// ---------------------------------------------------------------------------
__global__ __launch_bounds__(256) void gemm_o_fused(
    const float* __restrict__ Opart, const float* __restrict__ Mp,
    const float* __restrict__ Lp, const ushort_t* __restrict__ Bt,
    const float* __restrict__ bias, float* __restrict__ C) {
  __shared__ ushort_t As[64][64];
  __shared__ ushort_t Bs[64][64];
  const int tid  = threadIdx.x;
  const int wave = tid >> 6, lane = tid & 63;
  const int quad = lane >> 4, l15 = lane & 15;

  // T1 XCD-aware remap (grid (8,64) = 512, multiple of 8)
  const int nb  = blockIdx.x + blockIdx.y * gridDim.x;
  const int tot = gridDim.x * gridDim.y;
  const int wid = (nb & 7) * (tot >> 3) + (nb >> 3);
  const int bx  = wid % gridDim.x, by = wid / gridDim.x;
  const int m0 = by * 64, n0 = bx * 64;

  const int b  = m0 >> 11;        // batch of this row-tile
  const int qb = (m0 >> 6) & 31;  // q-block of this row-tile

  f32x4 acc[4] = {};

  // B staging (async16): per wave 16 rows, 2 insts
  const int lrow = lane >> 3, slot = lane & 7;
  const int cswz = 8 * (slot ^ lrow);
  const ushort_t* bg = Bt + (size_t)(n0 + wave * 16 + lrow) * DMODEL + cswz;
  ushort_t* lb0 = &Bs[wave * 16][0];
  ushort_t* lb1 = &Bs[wave * 16 + 8][0];

  // A combine-staging: thread -> row r (0..63), col-group g (16 cols)
  const int r = tid >> 2;
  const int g = tid & 3;
  const int rx = r & 7;

  const int swz = l15 & 7;

  for (int k0 = 0; k0 < DMODEL; k0 += 64) {
    const int h = k0 >> 6;
    const int pidx0 = b * 1024 + h * 128 + qb * 4;  // ((b*8+h)*32+qb)*NSPLIT
    __syncthreads();
    async16(bg + k0, lb0);
    async16(bg + k0 + 8 * (size_t)DMODEL, lb1);

    // per-row split weights (4 threads per row load the same scalars)
    const float* mp = Mp + (size_t)pidx0 * 64 + r;
    const float* lp = Lp + (size_t)pidx0 * 64 + r;
    float ms[4], ls[4];
#pragma unroll
    for (int s = 0; s < 4; s++) { ms[s] = mp[s * 64]; ls[s] = lp[s * 64]; }
    const float M = fmaxf(fmaxf(ms[0], ms[1]), fmaxf(ms[2], ms[3]));
    float wsp[4], L = 0.f;
#pragma unroll
    for (int s = 0; s < 4; s++) { wsp[s] = fexp2(ms[s] - M); L += ls[s] * wsp[s]; }
    const float rL = 1.0f / L;

    const float* pp = Opart + (size_t)pidx0 * 4096 + r * 64 + g * 16;
    float a[16];
#pragma unroll
    for (int q4 = 0; q4 < 4; q4++) {
      float4 x0 = *reinterpret_cast<const float4*>(pp + 0 * 4096 + q4 * 4);
      float4 x1 = *reinterpret_cast<const float4*>(pp + 1 * 4096 + q4 * 4);
      float4 x2 = *reinterpret_cast<const float4*>(pp + 2 * 4096 + q4 * 4);
      float4 x3 = *reinterpret_cast<const float4*>(pp + 3 * 4096 + q4 * 4);
      a[q4 * 4 + 0] = (x0.x * wsp[0] + x1.x * wsp[1] + x2.x * wsp[2] + x3.x * wsp[3]) * rL;
      a[q4 * 4 + 1] = (x0.y * wsp[0] + x1.y * wsp[1] + x2.y * wsp[2] + x3.y * wsp[3]) * rL;
      a[q4 * 4 + 2] = (x0.z * wsp[0] + x1.z * wsp[1] + x2.z * wsp[2] + x3.z * wsp[3]) * rL;
      a[q4 * 4 + 3] = (x0.w * wsp[0] + x1.w * wsp[1] + x2.w * wsp[2] + x3.w * wsp[3]) * rL;
    }
    int4v w0v, w1v;
#pragma unroll
    for (int i = 0; i < 4; i++) {
      w0v[i] = cvt_pk_bf16(a[2 * i], a[2 * i + 1]);
      w1v[i] = cvt_pk_bf16(a[8 + 2 * i], a[8 + 2 * i + 1]);
    }
    *reinterpret_cast<int4v*>(&As[r][8 * ((2 * g) ^ rx)]) = w0v;
    *reinterpret_cast<int4v*>(&As[r][8 * ((2 * g + 1) ^ rx)]) = w1v;

    asm volatile("s_waitcnt vmcnt(0)" ::: "memory");
    __syncthreads();
#pragma unroll
    for (int s = 0; s < 2; s++) {
      const int acol = 8 * ((s * 4 + quad) ^ swz);
      bf16x8 af = *reinterpret_cast<const bf16x8*>(&As[wave * 16 + l15][acol]);
#pragma unroll
      for (int t = 0; t < 4; t++) {
        bf16x8 bfr = *reinterpret_cast<const bf16x8*>(&Bs[t * 16 + l15][acol]);
        acc[t] = MFMA16(af, bfr, acc[t]);
      }
    }
  }

#pragma unroll
  for (int t = 0; t < 4; t++) {
    const int col = n0 + t * 16 + l15;
    const float bv = bias[col];
#pragma unroll
    for (int rr = 0; rr < 4; rr++) {
      const int row = m0 + wave * 16 + quad * 4 + rr;
      C[(size_t)row * DMODEL + col] = acc[t][rr] + bv;
    }
  }
}

// ---------------------------------------------------------------------------
// 3) Fused flash attention (R7-proven config: 256 thr, QBLK=64, packed DA,
//    NSPLIT=4 -> 2048 WGs; TLP dominates split-K write savings, per R8).
//    T1 XCD-aware work remap (h decoded fastest within each XCD chunk) +
//    T5 s_setprio(1) around the QK^T and PV MFMA clusters.
//    Q pre-scaled by 0.125*log2e -> log2-domain softmax. P/V use k'-permuted
//    contraction order (k' = 4*(k&15)+(k>>4)).
// ---------------------------------------------------------------------------
__global__ __launch_bounds__(256) void attn_kernel(
    const ushort_t* __restrict__ QKV, const uint_t* __restrict__ DA,
    const float* __restrict__ wd, const float* __restrict__ wa,
    float* __restrict__ Opart, float* __restrict__ Mp, float* __restrict__ Lp) {
  // T1: flat id over (32, 8, 8) grid; w = (n%8)*256 + n/8; decode h fastest.
  const int n = blockIdx.x + (blockIdx.y << 5) + (blockIdx.z << 8);  // 0..2047
  const int w = ((n & 7) << 8) | (n >> 3);
  const int h = w & 7;
  const int qb = (w >> 3) & 31;
  const int z = w >> 8;                      // 0..7
  const int b = z >> 2, split = z & 3;       // NSPLIT = 4
  const int tid = threadIdx.x;
  const int wave = tid >> 6, lane = tid & 63;
  const int quad = lane >> 4, l15 = lane & 15;
  const int q0 = qb * 64;
  const float wdh = wd[h] * L2E, wah = wa[h] * L2E;

  __shared__ ushort_t Ks[64][64];                 // K tile, XOR-swizzled col blocks
  __shared__ ushort_t Vts[64][64];                // V^T tile (k'-order), XOR-swizzled
  __shared__ __align__(16) ushort_t Ps[4][16][72]; // P (k'-order), +8 pad

  // Q fragments for this wave's 16-query stripe
  const int qrow = q0 + wave * 16 + l15;
  bf16x8 qf[2];
#pragma unroll
  for (int s = 0; s < 2; s++)
    qf[s] = *reinterpret_cast<const bf16x8*>(
        &QKV[(size_t)(b * SEQ + qrow) * NQKV + h * DK + s * 32 + quad * 8]);

  bf16x8 ones;
#pragma unroll
  for (int j = 0; j < 8; j++) ones[j] = (short)0x3F80;  // bf16 1.0

  float m_run[4], l_run[4];
  f32x4 o[4] = {};
#pragma unroll
  for (int rr = 0; rr < 4; rr++) { m_run[rr] = -INFINITY; l_run[rr] = 0.f; }

  // K staging (async): per wave 16 rows, 2 insts
  const int lrow = lane >> 3, slot = lane & 7;
  const ushort_t* kg = QKV + (size_t)(b * SEQ + wave * 16 + lrow) * NQKV +
                       512 + h * DK + 8 * (slot ^ lrow);
  ushort_t* lk0 = &Ks[wave * 16][0];
  ushort_t* lk1 = &Ks[wave * 16 + 8][0];

  // V staging (manual transpose into k'-order; k'(kv) == u, k'(kv+8) == u+32)
  const int u  = tid >> 3;                    // 0..31
  const int c7 = tid & 7;
  const int sc = c7 * 8;                      // d-offset this thread handles
  const int kv = ((u & 3) << 4) | (u >> 2);   // logical k row this thread loads
  const ushort_t* vg = QKV + (size_t)(b * SEQ + kv) * NQKV + 1024 + h * DK + sc;
  const int col0 = (u & 7) + 8 * ((u >> 3) ^ c7);
  const int col1 = (u & 7) + 8 * (((u >> 3) + 4) ^ c7);

  const int swz = l15 & 7;
  const uint_t* DArow = DA + (size_t)b * SEQ * SEQ;

  for (int kbi = 0; kbi < KB_PER; kbi++) {
    const int k0 = (split * KB_PER + kbi) * 64;
    __syncthreads();
    async16(kg + (size_t)k0 * NQKV, lk0);
    async16(kg + (size_t)(k0 + 8) * NQKV, lk1);
    bf16x8 v0 = *reinterpret_cast<const bf16x8*>(vg + (size_t)k0 * NQKV);
    bf16x8 v1 = *reinterpret_cast<const bf16x8*>(vg + (size_t)(k0 + 8) * NQKV);
#pragma unroll
    for (int j = 0; j < 8; j++) {
      Vts[sc + j][col0] = (ushort_t)v0[j];
      Vts[sc + j][col1] = (ushort_t)v1[j];
    }

    // issue bias loads now: they drain under the same vmcnt(0) as staging
    uint_t da[4][4];
#pragma unroll
    for (int t = 0; t < 4; t++) {
      const int kk = k0 + t * 16 + l15;
#pragma unroll
      for (int rr = 0; rr < 4; rr++) {
        const int qg = q0 + wave * 16 + quad * 4 + rr;
        da[t][rr] = DArow[(size_t)qg * SEQ + kk];
      }
    }

    asm volatile("s_waitcnt vmcnt(0)" ::: "memory");
    __syncthreads();

    // S(log2) = Q'K^T + wd'*D + wa'*A   (Q pre-scaled by 0.125*log2e)
    f32x4 sacc[4];
    __builtin_amdgcn_s_setprio(1);
#pragma unroll
    for (int t = 0; t < 4; t++) {
      bf16x8 kf0 = *reinterpret_cast<const bf16x8*>(&Ks[t * 16 + l15][8 * (quad ^ swz)]);
      bf16x8 kf1 = *reinterpret_cast<const bf16x8*>(&Ks[t * 16 + l15][8 * ((4 + quad) ^ swz)]);
      f32x4 z2 = {};
      z2 = MFMA16(qf[0], kf0, z2);
      sacc[t] = MFMA16(qf[1], kf1, z2);
    }
    __builtin_amdgcn_s_setprio(0);

    float sv[4][4];
    float mx[4] = {-INFINITY, -INFINITY, -INFINITY, -INFINITY};
#pragma unroll
    for (int t = 0; t < 4; t++) {
#pragma unroll
      for (int rr = 0; rr < 4; rr++) {
        const float fd = __builtin_bit_cast(float, da[t][rr] << 16);
        const float fa = __builtin_bit_cast(float, da[t][rr] & 0xFFFF0000u);
        float s = fmaf(wdh, fd, fmaf(wah, fa, sacc[t][rr]));
        sv[t][rr] = s;
        mx[rr] = fmaxf(mx[rr], s);
      }
    }
    // row max via DPP (lanes 0-15 of each quad-group == one DPP row)
#pragma unroll
    for (int rr = 0; rr < 4; rr++) mx[rr] = rowmax16(mx[rr]);

    // defer-max: only rescale when some row max grew by > ~8 nats (11.5 bits)
    bool grow = false;
#pragma unroll
    for (int rr = 0; rr < 4; rr++) grow |= (mx[rr] > m_run[rr] + 11.5f);
    if (__ballot(grow)) {
      float alpha[4];
#pragma unroll
      for (int rr = 0; rr < 4; rr++) {
        const float mn = fmaxf(m_run[rr], mx[rr]);
        alpha[rr] = fexp2(m_run[rr] - mn);
        m_run[rr] = mn;
        l_run[rr] *= alpha[rr];
      }
#pragma unroll
      for (int dt = 0; dt < 4; dt++)
#pragma unroll
        for (int rr = 0; rr < 4; rr++) o[dt][rr] *= alpha[rr];
    }

    // P = 2^(S - m), packed 2x bf16 per dword, 4 contiguous k' per b64 write
#pragma unroll
    for (int rr = 0; rr < 4; rr++) {
      const float m = m_run[rr];
      i32x2 wv2;
      wv2[0] = cvt_pk_bf16(fexp2(sv[0][rr] - m), fexp2(sv[1][rr] - m));
      wv2[1] = cvt_pk_bf16(fexp2(sv[2][rr] - m), fexp2(sv[3][rr] - m));
      *reinterpret_cast<i32x2*>(&Ps[wave][quad * 4 + rr][l15 * 4]) = wv2;
    }

    // Ps is wave-private: wave-local LDS drain is enough (no barrier)
    asm volatile("s_waitcnt lgkmcnt(0)" ::: "memory");

    // O += P @ V ; row-sum(P) via MFMA with all-ones B operand
    f32x4 rsacc = {};
    __builtin_amdgcn_s_setprio(1);
#pragma unroll
    for (int s2 = 0; s2 < 2; s2++) {
      bf16x8 pf = *reinterpret_cast<const bf16x8*>(&Ps[wave][l15][s2 * 32 + quad * 8]);
#pragma unroll
      for (int dt = 0; dt < 4; dt++) {
        const int vrow = dt * 16 + l15;
        const int vcb = (s2 * 4 + quad) ^ (vrow >> 3);
        bf16x8 vf = *reinterpret_cast<const bf16x8*>(&Vts[vrow][vcb * 8]);
        o[dt] = MFMA16(pf, vf, o[dt]);
      }
      rsacc = MFMA16(pf, ones, rsacc);
    }
    __builtin_amdgcn_s_setprio(0);
#pragma unroll
    for (int rr = 0; rr < 4; rr++) l_run[rr] += rsacc[rr];
  }

  // epilogue: write fp32 partials (un-normalized) + m, l
  const int pidx = (((b * NHEADS + h) * 32 + qb) * NSPLIT + split);
  float* op = Opart + (size_t)pidx * 4096;
#pragma unroll
  for (int dt = 0; dt < 4; dt++) {
#pragma unroll
    for (int rr = 0; rr < 4; rr++) {
      const int row = wave * 16 + quad * 4 + rr;
      op[row * 64 + dt * 16 + l15] = o[dt][rr];
    }
  }
  if (l15 == 0) {
#pragma unroll
    for (int rr = 0; rr < 4; rr++) {
      const int row = wave * 16 + quad * 4 + rr;
      Mp[(size_t)pidx * 64 + row] = m_run[rr];
      Lp[(size_t)pidx * 64 + row] = l_run[rr];
    }
  }
}

// ---------------------------------------------------------------------------
extern "C" void kernel_launch(void* const* d_in, const int* in_sizes, int n_in,
                              void* d_out, int out_size, void* d_ws, size_t ws_size,
                              hipStream_t stream) {
  const float* x  = (const float*)d_in[0];
  const float* Dm = (const float*)d_in[1];
  const float* Am = (const float*)d_in[2];
  const float* Wq = (const float*)d_in[3];
  const float* bq = (const float*)d_in[4];
  const float* Wk = (const float*)d_in[5];
  const float* bk = (const float*)d_in[6];
  const float* Wv = (const float*)d_in[7];
  const float* bv = (const float*)d_in[8];
  const float* Wo = (const float*)d_in[9];
  const float* bo = (const float*)d_in[10];
  const float* wd = (const float*)d_in[11];
  const float* wa = (const float*)d_in[12];

  char* ws = (char*)d_ws;
  size_t off = 0;
  ushort_t* xb    = (ushort_t*)(ws + off); off += (size_t)XE * 2;         // 4 MB
  ushort_t* wqkvb = (ushort_t*)(ws + off); off += (size_t)3 * WE * 2;     // 1.5 MB
  ushort_t* wob   = (ushort_t*)(ws + off); off += (size_t)WE * 2;         // 0.5 MB
  ushort_t* QKVb  = (ushort_t*)(ws + off); off += (size_t)MROWS * NQKV * 2; // 12 MB
  float*    bqkv  = (float*)(ws + off);    off += (size_t)NQKV * 4;       // 6 KB
  off = (off + 255) & ~(size_t)255;
  uint_t*   DAb   = (uint_t*)(ws + off);   off += (size_t)BATCH * SEQ * SEQ * 4; // 33.5 MB
  float*    Opart = (float*)(ws + off);    off += (size_t)512 * NSPLIT * 4096 * 4; // 33.5 MB
  float*    Mpart = (float*)(ws + off);    off += (size_t)512 * NSPLIT * 64 * 4;
  float*    Lpart = (float*)(ws + off);

  // 1) fused prep: convert to bf16 (+bias concat, Wq/bq pre-scaled) + D/A pack
  convert_pack_kernel<<<CONV_BLOCKS + 1 + PACK_BLOCKS, 256, 0, stream>>>(
      x, Wq, Wk, Wv, Wo, bq, bk, bv, Dm, Am, xb, bqkv, DAb);

  // 2) fused QKV projection: (4096 x 512) @ (1536 x 512)^T, 128x64 tiles
  dim3 qkvgrid(NQKV / 64, MROWS / 128);
  gemm_bt128x64<false><<<qkvgrid, 256, 0, stream>>>(xb, wqkvb, bqkv, QKVb, NQKV, DMODEL);

  // 3) fused attention (split-K=4, packed DA, XCD remap + setprio)
  dim3 agrid(SEQ / 64, NHEADS, BATCH * NSPLIT);
  attn_kernel<<<agrid, 256, 0, stream>>>(QKVb, DAb, wd, wa, Opart, Mpart, Lpart);

  // 4) FUSED combine + output projection (fp32 out), 64x64 tiles, 512 WGs
  dim3 ogrid(DMODEL / 64, MROWS / 64);
  gemm_o_fused<<<ogrid, 256, 0, stream>>>(Opart, Mpart, Lpart, wob, bo, (float*)d_out);
}

// Round 11
// 210.227 us; speedup vs baseline: 1.0222x; 1.0222x over previous
//
#include <hip/hip_runtime.h>
#include <hip/hip_bf16.h>
#include <math.h>

typedef unsigned short ushort_t;
typedef unsigned int   uint_t;
typedef __attribute__((ext_vector_type(8))) short  bf16x8;
typedef __attribute__((ext_vector_type(4))) float  f32x4;
typedef __attribute__((ext_vector_type(4))) int    int4v;
typedef __attribute__((ext_vector_type(2))) int    i32x2;
typedef __attribute__((ext_vector_type(4))) short  s16x4;

#define MFMA16(a, b, c) __builtin_amdgcn_mfma_f32_16x16x32_bf16((a), (b), (c), 0, 0, 0)

static constexpr int BATCH = 2;
static constexpr int SEQ   = 2048;
static constexpr int DMODEL = 512;
static constexpr int NHEADS = 8;
static constexpr int DK    = 64;
static constexpr int MROWS = BATCH * SEQ;          // 4096
static constexpr int XE = MROWS * DMODEL;          // 2097152 elems
static constexpr int WE = DMODEL * DMODEL;         // 262144 elems
static constexpr int NQKV = 3 * DMODEL;            // 1536 fused-projection cols
static constexpr int NSPLIT = 4;                   // split-K factor for attention
static constexpr int KB_PER = (SEQ / 64) / NSPLIT; // 8 k-blocks per split

// 0.125 (1/sqrt(DK)) * log2(e): folded into Wq/bq so softmax runs in log2 domain
static constexpr float QSCALE_L2E = 0.18033688011112043f;
static constexpr float L2E = 1.4426950408889634f;

__device__ __forceinline__ ushort_t f2bf(float f) {
  unsigned int u = __builtin_bit_cast(unsigned int, f);
  u = (u + 0x7FFFu + ((u >> 16) & 1u)) >> 16;
  return (ushort_t)u;
}

// 2^x via v_exp_f32 (no pre-multiply)
__device__ __forceinline__ float fexp2(float x) {
  float r;
  asm("v_exp_f32 %0, %1" : "=v"(r) : "v"(x));
  return r;
}

// pack 2 f32 -> 2 bf16 (RNE), lo <- a, hi <- b
__device__ __forceinline__ int cvt_pk_bf16(float a, float b) {
  int r;
  asm("v_cvt_pk_bf16_f32 %0, %1, %2" : "=v"(r) : "v"(a), "v"(b));
  return r;
}

// max across the 16 lanes of a DPP row (lanes 0-15 / 16-31 / ...), pure VALU
__device__ __forceinline__ float rowmax16(float x) {
  int t;
  t = __builtin_amdgcn_mov_dpp(__builtin_bit_cast(int, x), 0xB1, 0xF, 0xF, true);   // quad_perm [1,0,3,2]
  x = fmaxf(x, __builtin_bit_cast(float, t));
  t = __builtin_amdgcn_mov_dpp(__builtin_bit_cast(int, x), 0x4E, 0xF, 0xF, true);   // quad_perm [2,3,0,1]
  x = fmaxf(x, __builtin_bit_cast(float, t));
  t = __builtin_amdgcn_mov_dpp(__builtin_bit_cast(int, x), 0x141, 0xF, 0xF, true);  // row_half_mirror (xor4)
  x = fmaxf(x, __builtin_bit_cast(float, t));
  t = __builtin_amdgcn_mov_dpp(__builtin_bit_cast(int, x), 0x140, 0xF, 0xF, true);  // row_mirror (xor8)
  x = fmaxf(x, __builtin_bit_cast(float, t));
  return x;
}

// async 16B/lane global -> LDS (lands at lds_base + lane*16)
__device__ __forceinline__ void async16(const ushort_t* g, ushort_t* l) {
  __builtin_amdgcn_global_load_lds(
      (const __attribute__((address_space(1))) unsigned int*)g,
      (__attribute__((address_space(3))) unsigned int*)l, 16, 0, 0);
}

// ---------------------------------------------------------------------------
// 1) Fused prep kernel (ONE launch):
//    - fp32 -> bf16 convert of x, Wq, Wk, Wv, Wo (Wq/bq pre-scaled by
//      0.125*log2e -> log2-domain softmax)
//    - bias concat block
//    - D,A fp32 -> interleaved bf16 pack (lo16 = D, hi16 = A)
// ---------------------------------------------------------------------------
static constexpr int CONV_BLOCKS = (XE + 4 * WE) / 1024;          // 2560
static constexpr int PACK_BLOCKS = (BATCH * SEQ * SEQ) / 1024;    // 8192

__global__ __launch_bounds__(256) void convert_pack_kernel(
    const float* __restrict__ x,  const float* __restrict__ wq,
    const float* __restrict__ wk, const float* __restrict__ wv,
    const float* __restrict__ wo,
    const float* __restrict__ bq, const float* __restrict__ bk,
    const float* __restrict__ bv,
    const float* __restrict__ Dm, const float* __restrict__ Am,
    ushort_t* __restrict__ dst, float* __restrict__ bqkv,
    uint_t* __restrict__ DAb) {
  const int bid = blockIdx.x;
  if (bid == CONV_BLOCKS) {  // bias-concat block
    for (int i = threadIdx.x; i < NQKV; i += 256) {
      bqkv[i] = (i < 512) ? bq[i] * QSCALE_L2E
              : (i < 1024) ? bk[i - 512] : bv[i - 1024];
    }
    return;
  }
  if (bid > CONV_BLOCKS) {  // D/A pack blocks
    int e = ((bid - CONV_BLOCKS - 1) * 256 + threadIdx.x) * 4;
    float4 d = *reinterpret_cast<const float4*>(&Dm[e]);
    float4 a = *reinterpret_cast<const float4*>(&Am[e]);
    int4v v;
    v[0] = (int)((uint_t)f2bf(d.x) | ((uint_t)f2bf(a.x) << 16));
    v[1] = (int)((uint_t)f2bf(d.y) | ((uint_t)f2bf(a.y) << 16));
    v[2] = (int)((uint_t)f2bf(d.z) | ((uint_t)f2bf(a.z) << 16));
    v[3] = (int)((uint_t)f2bf(d.w) | ((uint_t)f2bf(a.w) << 16));
    *reinterpret_cast<int4v*>(&DAb[e]) = v;
    return;
  }
  int e = (bid * 256 + threadIdx.x) * 4;
  const float* src;
  int off;
  float qs = 1.0f;
  if (e < XE)                { src = x;  off = e; }
  else if (e < XE + WE)      { src = wq; off = e - XE; qs = QSCALE_L2E; }
  else if (e < XE + 2 * WE)  { src = wk; off = e - XE - WE; }
  else if (e < XE + 3 * WE)  { src = wv; off = e - XE - 2 * WE; }
  else                       { src = wo; off = e - XE - 3 * WE; }
  float4 f = *reinterpret_cast<const float4*>(&src[off]);
  s16x4 v;
  v[0] = (short)f2bf(f.x * qs); v[1] = (short)f2bf(f.y * qs);
  v[2] = (short)f2bf(f.z * qs); v[3] = (short)f2bf(f.w * qs);
  *reinterpret_cast<s16x4*>(&dst[e]) = v;
}

// ---------------------------------------------------------------------------
// 2a) bf16 GEMM, 128x64 tile / WG (4 waves, each owning a 64x32 quadrant).
//     Used for the QKV projection (grid 24x32 = 768 WGs = 3/CU).
//     T1 XCD-aware block remap. XOR-swizzle invariant:
//     LDS[r][slot*8+j] holds global col-block (slot ^ (r&7)) of the k-tile;
//     fragment read at col 8*((blk) ^ (l15&7)).
// ---------------------------------------------------------------------------
template <bool F32OUT>
__global__ __launch_bounds__(256) void gemm_bt128x64(
    const ushort_t* __restrict__ A, const ushort_t* __restrict__ Bt,
    const float* __restrict__ bias, void* __restrict__ C,
    int N, int K) {
  __shared__ ushort_t As[128][64];
  __shared__ ushort_t Bs[64][64];
  const int tid  = threadIdx.x;
  const int wave = tid >> 6, lane = tid & 63;
  const int quad = lane >> 4, l15 = lane & 15;

  // T1 XCD-aware remap (grid sizes are multiples of 8)
  const int nb  = blockIdx.x + blockIdx.y * gridDim.x;
  const int tot = gridDim.x * gridDim.y;
  const int w   = (nb & 7) * (tot >> 3) + (nb >> 3);
  const int bx  = w % gridDim.x, by = w / gridDim.x;
  const int m0 = by * 128, n0 = bx * 64;
  const int wr = (wave >> 1) * 64, wc = (wave & 1) * 32;  // wave's C quadrant

  f32x4 acc[4][2] = {};

  // staging: A 128 rows (4 x async16/wave), B 64 rows (2 x async16/wave)
  const int lrow = lane >> 3, slot = lane & 7;
  const int cswz = 8 * (slot ^ lrow);
  const ushort_t* ag = A  + (size_t)(m0 + wave * 8 + lrow) * K + cswz;
  const ushort_t* bg = Bt + (size_t)(n0 + wave * 16 + lrow) * K + cswz;
  ushort_t* la[4];
#pragma unroll
  for (int r0 = 0; r0 < 4; r0++) la[r0] = &As[r0 * 32 + wave * 8][0];
  ushort_t* lb0 = &Bs[wave * 16][0];
  ushort_t* lb1 = &Bs[wave * 16 + 8][0];

  const int swz = l15 & 7;

  for (int k0 = 0; k0 < K; k0 += 64) {
    __syncthreads();
#pragma unroll
    for (int r0 = 0; r0 < 4; r0++)
      async16(ag + k0 + (size_t)(r0 * 32) * K, la[r0]);
    async16(bg + k0, lb0);
    async16(bg + k0 + 8 * (size_t)K, lb1);
    asm volatile("s_waitcnt vmcnt(0)" ::: "memory");
    __syncthreads();
#pragma unroll
    for (int s = 0; s < 2; s++) {
      const int acol = 8 * ((s * 4 + quad) ^ swz);
      bf16x8 af[4], bfr[2];
#pragma unroll
      for (int i = 0; i < 4; i++)
        af[i] = *reinterpret_cast<const bf16x8*>(&As[wr + i * 16 + l15][acol]);
#pragma unroll
      for (int j = 0; j < 2; j++)
        bfr[j] = *reinterpret_cast<const bf16x8*>(&Bs[wc + j * 16 + l15][acol]);
#pragma unroll
      for (int i = 0; i < 4; i++)
#pragma unroll
        for (int j = 0; j < 2; j++)
          acc[i][j] = MFMA16(af[i], bfr[j], acc[i][j]);
    }
  }

#pragma unroll
  for (int j = 0; j < 2; j++) {
    const int col = n0 + wc + j * 16 + l15;
    const float bv = bias[col];
#pragma unroll
    for (int i = 0; i < 4; i++) {
#pragma unroll
      for (int rr = 0; rr < 4; rr++) {
        const int row = m0 + wr + i * 16 + quad * 4 + rr;
        const float v = acc[i][j][rr] + bv;
        if (F32OUT) reinterpret_cast<float*>(C)[(size_t)row * N + col] = v;
        else        reinterpret_cast<ushort_t*>(C)[(size_t)row * N + col] = f2bf(v);
      }
    }
  }
}

// ---------------------------------------------------------------------------
// 2b) bf16 GEMM, 64x64 tile / WG (4 waves, each owning a 16-row stripe).
//     Used for the O-projection: grid (8, 64) = 512 WGs = 2 WG/CU.
//     Same XOR-swizzle invariant; T1 remap.
// ---------------------------------------------------------------------------
template <bool F32OUT>
__global__ __launch_bounds__(256) void gemm_bt64(
    const ushort_t* __restrict__ A, const ushort_t* __restrict__ Bt,
    const float* __restrict__ bias, void* __restrict__ C,
    int N, int K) {
  __shared__ ushort_t As[64][64];
  __shared__ ushort_t Bs[64][64];
  const int tid  = threadIdx.x;
  const int wave = tid >> 6, lane = tid & 63;
  const int quad = lane >> 4, l15 = lane & 15;

  // T1 XCD-aware remap (grid sizes are multiples of 8)
  const int nb  = blockIdx.x + blockIdx.y * gridDim.x;
  const int tot = gridDim.x * gridDim.y;
  const int w   = (nb & 7) * (tot >> 3) + (nb >> 3);
  const int bx  = w % gridDim.x, by = w / gridDim.x;
  const int m0 = by * 64, n0 = bx * 64;

  f32x4 acc[4] = {};

  const int lrow = lane >> 3, slot = lane & 7;
  const int cswz = 8 * (slot ^ lrow);
  const ushort_t* ag = A  + (size_t)(m0 + wave * 16 + lrow) * K + cswz;
  const ushort_t* bg = Bt + (size_t)(n0 + wave * 16 + lrow) * K + cswz;
  ushort_t* la0 = &As[wave * 16][0];
  ushort_t* la1 = &As[wave * 16 + 8][0];
  ushort_t* lb0 = &Bs[wave * 16][0];
  ushort_t* lb1 = &Bs[wave * 16 + 8][0];

  const int swz = l15 & 7;

  for (int k0 = 0; k0 < K; k0 += 64) {
    __syncthreads();
    async16(ag + k0, la0);
    async16(ag + k0 + 8 * (size_t)K, la1);
    async16(bg + k0, lb0);
    async16(bg + k0 + 8 * (size_t)K, lb1);
    asm volatile("s_waitcnt vmcnt(0)" ::: "memory");
    __syncthreads();
#pragma unroll
    for (int s = 0; s < 2; s++) {
      const int acol = 8 * ((s * 4 + quad) ^ swz);
      bf16x8 af = *reinterpret_cast<const bf16x8*>(&As[wave * 16 + l15][acol]);
#pragma unroll
      for (int t = 0; t < 4; t++) {
        bf16x8 bfr = *reinterpret_cast<const bf16x8*>(&Bs[t * 16 + l15][acol]);
        acc[t] = MFMA16(af, bfr, acc[t]);
      }
    }
  }

#pragma unroll
  for (int t = 0; t < 4; t++) {
    const int col = n0 + t * 16 + l15;
    const float bv = bias[col];
#pragma unroll
    for (int rr = 0; rr < 4; rr++) {
      const int row = m0 + wave * 16 + quad * 4 + rr;
      const float v = acc[t][rr] + bv;
      if (F32OUT) reinterpret_cast<float*>(C)[(size_t)row * N + col] = v;
      else        reinterpret_cast<ushort_t*>(C)[(size_t)row * N + col] = f2bf(v);
    }
  }
}

// ---------------------------------------------------------------------------
// 3) Fused flash attention (R7-proven config: 256 thr, QBLK=64, packed DA,
//    NSPLIT=4 -> 2048 WGs; TLP dominates split-K write savings, per R8).
//    T1 XCD-aware work remap (h decoded fastest within each XCD chunk) +
//    T5 s_setprio(1) around the QK^T and PV MFMA clusters.
//    Q pre-scaled by 0.125*log2e -> log2-domain softmax. P/V use k'-permuted
//    contraction order (k' = 4*(k&15)+(k>>4)).
// ---------------------------------------------------------------------------
__global__ __launch_bounds__(256) void attn_kernel(
    const ushort_t* __restrict__ QKV, const uint_t* __restrict__ DA,
    const float* __restrict__ wd, const float* __restrict__ wa,
    float* __restrict__ Opart, float* __restrict__ Mp, float* __restrict__ Lp) {
  // T1: flat id over (32, 8, 8) grid; w = (n%8)*256 + n/8; decode h fastest.
  const int n = blockIdx.x + (blockIdx.y << 5) + (blockIdx.z << 8);  // 0..2047
  const int w = ((n & 7) << 8) | (n >> 3);
  const int h = w & 7;
  const int qb = (w >> 3) & 31;
  const int z = w >> 8;                      // 0..7
  const int b = z >> 2, split = z & 3;       // NSPLIT = 4
  const int tid = threadIdx.x;
  const int wave = tid >> 6, lane = tid & 63;
  const int quad = lane >> 4, l15 = lane & 15;
  const int q0 = qb * 64;
  const float wdh = wd[h] * L2E, wah = wa[h] * L2E;

  __shared__ ushort_t Ks[64][64];                 // K tile, XOR-swizzled col blocks
  __shared__ ushort_t Vts[64][64];                // V^T tile (k'-order), XOR-swizzled
  __shared__ __align__(16) ushort_t Ps[4][16][72]; // P (k'-order), +8 pad

  // Q fragments for this wave's 16-query stripe
  const int qrow = q0 + wave * 16 + l15;
  bf16x8 qf[2];
#pragma unroll
  for (int s = 0; s < 2; s++)
    qf[s] = *reinterpret_cast<const bf16x8*>(
        &QKV[(size_t)(b * SEQ + qrow) * NQKV + h * DK + s * 32 + quad * 8]);

  bf16x8 ones;
#pragma unroll
  for (int j = 0; j < 8; j++) ones[j] = (short)0x3F80;  // bf16 1.0

  float m_run[4], l_run[4];
  f32x4 o[4] = {};
#pragma unroll
  for (int rr = 0; rr < 4; rr++) { m_run[rr] = -INFINITY; l_run[rr] = 0.f; }

  // K staging (async): per wave 16 rows, 2 insts
  const int lrow = lane >> 3, slot = lane & 7;
  const ushort_t* kg = QKV + (size_t)(b * SEQ + wave * 16 + lrow) * NQKV +
                       512 + h * DK + 8 * (slot ^ lrow);
  ushort_t* lk0 = &Ks[wave * 16][0];
  ushort_t* lk1 = &Ks[wave * 16 + 8][0];

  // V staging (manual transpose into k'-order; k'(kv) == u, k'(kv+8) == u+32)
  const int u  = tid >> 3;                    // 0..31
  const int c7 = tid & 7;
  const int sc = c7 * 8;                      // d-offset this thread handles
  const int kv = ((u & 3) << 4) | (u >> 2);   // logical k row this thread loads
  const ushort_t* vg = QKV + (size_t)(b * SEQ + kv) * NQKV + 1024 + h * DK + sc;
  const int col0 = (u & 7) + 8 * ((u >> 3) ^ c7);
  const int col1 = (u & 7) + 8 * (((u >> 3) + 4) ^ c7);

  const int swz = l15 & 7;
  const uint_t* DArow = DA + (size_t)b * SEQ * SEQ;

  for (int kbi = 0; kbi < KB_PER; kbi++) {
    const int k0 = (split * KB_PER + kbi) * 64;
    __syncthreads();
    async16(kg + (size_t)k0 * NQKV, lk0);
    async16(kg + (size_t)(k0 + 8) * NQKV, lk1);
    bf16x8 v0 = *reinterpret_cast<const bf16x8*>(vg + (size_t)k0 * NQKV);
    bf16x8 v1 = *reinterpret_cast<const bf16x8*>(vg + (size_t)(k0 + 8) * NQKV);
#pragma unroll
    for (int j = 0; j < 8; j++) {
      Vts[sc + j][col0] = (ushort_t)v0[j];
      Vts[sc + j][col1] = (ushort_t)v1[j];
    }

    // issue bias loads now: they drain under the same vmcnt(0) as staging
    uint_t da[4][4];
#pragma unroll
    for (int t = 0; t < 4; t++) {
      const int kk = k0 + t * 16 + l15;
#pragma unroll
      for (int rr = 0; rr < 4; rr++) {
        const int qg = q0 + wave * 16 + quad * 4 + rr;
        da[t][rr] = DArow[(size_t)qg * SEQ + kk];
      }
    }

    asm volatile("s_waitcnt vmcnt(0)" ::: "memory");
    __syncthreads();

    // S(log2) = Q'K^T + wd'*D + wa'*A   (Q pre-scaled by 0.125*log2e)
    f32x4 sacc[4];
    __builtin_amdgcn_s_setprio(1);
#pragma unroll
    for (int t = 0; t < 4; t++) {
      bf16x8 kf0 = *reinterpret_cast<const bf16x8*>(&Ks[t * 16 + l15][8 * (quad ^ swz)]);
      bf16x8 kf1 = *reinterpret_cast<const bf16x8*>(&Ks[t * 16 + l15][8 * ((4 + quad) ^ swz)]);
      f32x4 z2 = {};
      z2 = MFMA16(qf[0], kf0, z2);
      sacc[t] = MFMA16(qf[1], kf1, z2);
    }
    __builtin_amdgcn_s_setprio(0);

    float sv[4][4];
    float mx[4] = {-INFINITY, -INFINITY, -INFINITY, -INFINITY};
#pragma unroll
    for (int t = 0; t < 4; t++) {
#pragma unroll
      for (int rr = 0; rr < 4; rr++) {
        const float fd = __builtin_bit_cast(float, da[t][rr] << 16);
        const float fa = __builtin_bit_cast(float, da[t][rr] & 0xFFFF0000u);
        float s = fmaf(wdh, fd, fmaf(wah, fa, sacc[t][rr]));
        sv[t][rr] = s;
        mx[rr] = fmaxf(mx[rr], s);
      }
    }
    // row max via DPP (lanes 0-15 of each quad-group == one DPP row)
#pragma unroll
    for (int rr = 0; rr < 4; rr++) mx[rr] = rowmax16(mx[rr]);

    // defer-max: only rescale when some row max grew by > ~8 nats (11.5 bits)
    bool grow = false;
#pragma unroll
    for (int rr = 0; rr < 4; rr++) grow |= (mx[rr] > m_run[rr] + 11.5f);
    if (__ballot(grow)) {
      float alpha[4];
#pragma unroll
      for (int rr = 0; rr < 4; rr++) {
        const float mn = fmaxf(m_run[rr], mx[rr]);
        alpha[rr] = fexp2(m_run[rr] - mn);
        m_run[rr] = mn;
        l_run[rr] *= alpha[rr];
      }
#pragma unroll
      for (int dt = 0; dt < 4; dt++)
#pragma unroll
        for (int rr = 0; rr < 4; rr++) o[dt][rr] *= alpha[rr];
    }

    // P = 2^(S - m), packed 2x bf16 per dword, 4 contiguous k' per b64 write
#pragma unroll
    for (int rr = 0; rr < 4; rr++) {
      const float m = m_run[rr];
      i32x2 wv2;
      wv2[0] = cvt_pk_bf16(fexp2(sv[0][rr] - m), fexp2(sv[1][rr] - m));
      wv2[1] = cvt_pk_bf16(fexp2(sv[2][rr] - m), fexp2(sv[3][rr] - m));
      *reinterpret_cast<i32x2*>(&Ps[wave][quad * 4 + rr][l15 * 4]) = wv2;
    }

    // Ps is wave-private: wave-local LDS drain is enough (no barrier)
    asm volatile("s_waitcnt lgkmcnt(0)" ::: "memory");

    // O += P @ V ; row-sum(P) via MFMA with all-ones B operand
    f32x4 rsacc = {};
    __builtin_amdgcn_s_setprio(1);
#pragma unroll
    for (int s2 = 0; s2 < 2; s2++) {
      bf16x8 pf = *reinterpret_cast<const bf16x8*>(&Ps[wave][l15][s2 * 32 + quad * 8]);
#pragma unroll
      for (int dt = 0; dt < 4; dt++) {
        const int vrow = dt * 16 + l15;
        const int vcb = (s2 * 4 + quad) ^ (vrow >> 3);
        bf16x8 vf = *reinterpret_cast<const bf16x8*>(&Vts[vrow][vcb * 8]);
        o[dt] = MFMA16(pf, vf, o[dt]);
      }
      rsacc = MFMA16(pf, ones, rsacc);
    }
    __builtin_amdgcn_s_setprio(0);
#pragma unroll
    for (int rr = 0; rr < 4; rr++) l_run[rr] += rsacc[rr];
  }

  // epilogue: write fp32 partials (un-normalized) + m, l
  const int pidx = (((b * NHEADS + h) * 32 + qb) * NSPLIT + split);
  float* op = Opart + (size_t)pidx * 4096;
#pragma unroll
  for (int dt = 0; dt < 4; dt++) {
#pragma unroll
    for (int rr = 0; rr < 4; rr++) {
      const int row = wave * 16 + quad * 4 + rr;
      op[row * 64 + dt * 16 + l15] = o[dt][rr];
    }
  }
  if (l15 == 0) {
#pragma unroll
    for (int rr = 0; rr < 4; rr++) {
      const int row = wave * 16 + quad * 4 + rr;
      Mp[(size_t)pidx * 64 + row] = m_run[rr];
      Lp[(size_t)pidx * 64 + row] = l_run[rr];
    }
  }
}

// ---------------------------------------------------------------------------
// 3b) split-K combine (m is in log2 domain -> exp2). Grid z = BATCH*4:
//     each block handles a 4-row chunk (rs) of its q-block -> 2048 WGs
//     (4x the TLP of the 16-row-loop version; pure streaming kernel).
// ---------------------------------------------------------------------------
__global__ __launch_bounds__(256) void combine_kernel(
    const float* __restrict__ Opart, const float* __restrict__ Mp,
    const float* __restrict__ Lp, ushort_t* __restrict__ AO) {
  const int qb = blockIdx.x, h = blockIdx.y;
  const int b = blockIdx.z >> 2, rs = blockIdx.z & 3;
  const int tid = threadIdx.x;
  const int lane = tid & 63, wq = tid >> 6;
  const int pidx0 = ((b * NHEADS + h) * 32 + qb) * NSPLIT;

  for (int r = rs * 4; r < rs * 4 + 4; r++) {
    const int q = wq * 16 + r;
    float m[NSPLIT], l[NSPLIT];
    float M = -INFINITY;
#pragma unroll
    for (int s = 0; s < NSPLIT; s++) {
      m[s] = Mp[(size_t)(pidx0 + s) * 64 + q];
      l[s] = Lp[(size_t)(pidx0 + s) * 64 + q];
      M = fmaxf(M, m[s]);
    }
    float L = 0.f, acc = 0.f;
#pragma unroll
    for (int s = 0; s < NSPLIT; s++) {
      const float w = fexp2(m[s] - M);
      L += l[s] * w;
      acc += Opart[(size_t)(pidx0 + s) * 4096 + q * 64 + lane] * w;
    }
    const int row = b * SEQ + qb * 64 + q;
    AO[(size_t)row * DMODEL + h * DK + lane] = f2bf(acc / L);
  }
}

// ---------------------------------------------------------------------------
extern "C" void kernel_launch(void* const* d_in, const int* in_sizes, int n_in,
                              void* d_out, int out_size, void* d_ws, size_t ws_size,
                              hipStream_t stream) {
  const float* x  = (const float*)d_in[0];
  const float* Dm = (const float*)d_in[1];
  const float* Am = (const float*)d_in[2];
  const float* Wq = (const float*)d_in[3];
  const float* bq = (const float*)d_in[4];
  const float* Wk = (const float*)d_in[5];
  const float* bk = (const float*)d_in[6];
  const float* Wv = (const float*)d_in[7];
  const float* bv = (const float*)d_in[8];
  const float* Wo = (const float*)d_in[9];
  const float* bo = (const float*)d_in[10];
  const float* wd = (const float*)d_in[11];
  const float* wa = (const float*)d_in[12];

  char* ws = (char*)d_ws;
  size_t off = 0;
  ushort_t* xb    = (ushort_t*)(ws + off); off += (size_t)XE * 2;         // 4 MB
  ushort_t* wqkvb = (ushort_t*)(ws + off); off += (size_t)3 * WE * 2;     // 1.5 MB
  ushort_t* wob   = (ushort_t*)(ws + off); off += (size_t)WE * 2;         // 0.5 MB
  ushort_t* QKVb  = (ushort_t*)(ws + off); off += (size_t)MROWS * NQKV * 2; // 12 MB
  ushort_t* AO    = (ushort_t*)(ws + off); off += (size_t)XE * 2;         // 4 MB
  float*    bqkv  = (float*)(ws + off);    off += (size_t)NQKV * 4;       // 6 KB
  off = (off + 255) & ~(size_t)255;
  uint_t*   DAb   = (uint_t*)(ws + off);   off += (size_t)BATCH * SEQ * SEQ * 4; // 33.5 MB
  float*    Opart = (float*)(ws + off);    off += (size_t)512 * NSPLIT * 4096 * 4; // 33.5 MB
  float*    Mpart = (float*)(ws + off);    off += (size_t)512 * NSPLIT * 64 * 4;
  float*    Lpart = (float*)(ws + off);

  // 1) fused prep: convert to bf16 (+bias concat, Wq/bq pre-scaled) + D/A pack
  convert_pack_kernel<<<CONV_BLOCKS + 1 + PACK_BLOCKS, 256, 0, stream>>>(
      x, Wq, Wk, Wv, Wo, bq, bk, bv, Dm, Am, xb, bqkv, DAb);

  // 2) fused QKV projection: (4096 x 512) @ (1536 x 512)^T, 128x64 tiles
  dim3 qkvgrid(NQKV / 64, MROWS / 128);
  gemm_bt128x64<false><<<qkvgrid, 256, 0, stream>>>(xb, wqkvb, bqkv, QKVb, NQKV, DMODEL);

  // 3) fused attention (split-K=4, packed DA, XCD remap + setprio) + combine
  dim3 agrid(SEQ / 64, NHEADS, BATCH * NSPLIT);
  attn_kernel<<<agrid, 256, 0, stream>>>(QKVb, DAb, wd, wa, Opart, Mpart, Lpart);
  dim3 cgrid(SEQ / 64, NHEADS, BATCH * 4);
  combine_kernel<<<cgrid, 256, 0, stream>>>(Opart, Mpart, Lpart, AO);

  // 4) output projection (fp32 out), 64x64 tiles (512 WGs = 2/CU)
  dim3 ogrid(DMODEL / 64, MROWS / 64);
  gemm_bt64<true><<<ogrid, 256, 0, stream>>>(AO, wob, bo, (float*)d_out, DMODEL, DMODEL);
}

// Round 12
// 209.701 us; speedup vs baseline: 1.0247x; 1.0025x over previous
//
#include <hip/hip_runtime.h>
#include <hip/hip_bf16.h>
#include <math.h>

typedef unsigned short ushort_t;
typedef unsigned int   uint_t;
typedef __attribute__((ext_vector_type(8))) short  bf16x8;
typedef __attribute__((ext_vector_type(4))) float  f32x4;
typedef __attribute__((ext_vector_type(4))) int    int4v;
typedef __attribute__((ext_vector_type(2))) int    i32x2;
typedef __attribute__((ext_vector_type(4))) short  s16x4;

#define MFMA16(a, b, c) __builtin_amdgcn_mfma_f32_16x16x32_bf16((a), (b), (c), 0, 0, 0)

static constexpr int BATCH = 2;
static constexpr int SEQ   = 2048;
static constexpr int DMODEL = 512;
static constexpr int NHEADS = 8;
static constexpr int DK    = 64;
static constexpr int MROWS = BATCH * SEQ;          // 4096
static constexpr int XE = MROWS * DMODEL;          // 2097152 elems
static constexpr int WE = DMODEL * DMODEL;         // 262144 elems
static constexpr int NQKV = 3 * DMODEL;            // 1536 fused-projection cols
static constexpr int NSPLIT = 4;                   // split-K factor for attention
static constexpr int KB_PER = (SEQ / 64) / NSPLIT; // 8 k-blocks per split

// 0.125 (1/sqrt(DK)) * log2(e): folded into Wq/bq so softmax runs in log2 domain
static constexpr float QSCALE_L2E = 0.18033688011112043f;
static constexpr float L2E = 1.4426950408889634f;

__device__ __forceinline__ ushort_t f2bf(float f) {
  unsigned int u = __builtin_bit_cast(unsigned int, f);
  u = (u + 0x7FFFu + ((u >> 16) & 1u)) >> 16;
  return (ushort_t)u;
}

// 2^x via v_exp_f32 (no pre-multiply)
__device__ __forceinline__ float fexp2(float x) {
  float r;
  asm("v_exp_f32 %0, %1" : "=v"(r) : "v"(x));
  return r;
}

// pack 2 f32 -> 2 bf16 (RNE), lo <- a, hi <- b  (single instruction)
__device__ __forceinline__ int cvt_pk_bf16(float a, float b) {
  int r;
  asm("v_cvt_pk_bf16_f32 %0, %1, %2" : "=v"(r) : "v"(a), "v"(b));
  return r;
}

// max across the 16 lanes of a DPP row (lanes 0-15 / 16-31 / ...), pure VALU
__device__ __forceinline__ float rowmax16(float x) {
  int t;
  t = __builtin_amdgcn_mov_dpp(__builtin_bit_cast(int, x), 0xB1, 0xF, 0xF, true);   // quad_perm [1,0,3,2]
  x = fmaxf(x, __builtin_bit_cast(float, t));
  t = __builtin_amdgcn_mov_dpp(__builtin_bit_cast(int, x), 0x4E, 0xF, 0xF, true);   // quad_perm [2,3,0,1]
  x = fmaxf(x, __builtin_bit_cast(float, t));
  t = __builtin_amdgcn_mov_dpp(__builtin_bit_cast(int, x), 0x141, 0xF, 0xF, true);  // row_half_mirror (xor4)
  x = fmaxf(x, __builtin_bit_cast(float, t));
  t = __builtin_amdgcn_mov_dpp(__builtin_bit_cast(int, x), 0x140, 0xF, 0xF, true);  // row_mirror (xor8)
  x = fmaxf(x, __builtin_bit_cast(float, t));
  return x;
}

// async 16B/lane global -> LDS (lands at lds_base + lane*16)
__device__ __forceinline__ void async16(const ushort_t* g, ushort_t* l) {
  __builtin_amdgcn_global_load_lds(
      (const __attribute__((address_space(1))) unsigned int*)g,
      (__attribute__((address_space(3))) unsigned int*)l, 16, 0, 0);
}

// ---------------------------------------------------------------------------
// 1) Fused prep kernel (ONE launch), 8 elements per thread, cvt_pk packing:
//    - fp32 -> bf16 convert of x, Wq, Wk, Wv, Wo (Wq/bq pre-scaled by
//      0.125*log2e -> log2-domain softmax): 1 cvt_pk per pair (was 4 ops/elem)
//    - bias concat block
//    - D,A fp32 -> interleaved bf16 pack (lo16 = D, hi16 = A): 1 cvt_pk per
//      element (was ~9 ops). Same RNE rounding as f2bf.
// ---------------------------------------------------------------------------
static constexpr int CONV_BLOCKS = (XE + 4 * WE) / 2048;          // 1280
static constexpr int PACK_BLOCKS = (BATCH * SEQ * SEQ) / 2048;    // 4096

__global__ __launch_bounds__(256) void convert_pack_kernel(
    const float* __restrict__ x,  const float* __restrict__ wq,
    const float* __restrict__ wk, const float* __restrict__ wv,
    const float* __restrict__ wo,
    const float* __restrict__ bq, const float* __restrict__ bk,
    const float* __restrict__ bv,
    const float* __restrict__ Dm, const float* __restrict__ Am,
    ushort_t* __restrict__ dst, float* __restrict__ bqkv,
    uint_t* __restrict__ DAb) {
  const int bid = blockIdx.x;
  if (bid == CONV_BLOCKS) {  // bias-concat block
    for (int i = threadIdx.x; i < NQKV; i += 256) {
      bqkv[i] = (i < 512) ? bq[i] * QSCALE_L2E
              : (i < 1024) ? bk[i - 512] : bv[i - 1024];
    }
    return;
  }
  if (bid > CONV_BLOCKS) {  // D/A pack blocks: 8 elems/thread, 2 cvt_pk x4
    int e = ((bid - CONV_BLOCKS - 1) * 256 + threadIdx.x) * 8;
    float4 d0 = *reinterpret_cast<const float4*>(&Dm[e]);
    float4 d1 = *reinterpret_cast<const float4*>(&Dm[e + 4]);
    float4 a0 = *reinterpret_cast<const float4*>(&Am[e]);
    float4 a1 = *reinterpret_cast<const float4*>(&Am[e + 4]);
    int4v v0, v1;
    v0[0] = cvt_pk_bf16(d0.x, a0.x); v0[1] = cvt_pk_bf16(d0.y, a0.y);
    v0[2] = cvt_pk_bf16(d0.z, a0.z); v0[3] = cvt_pk_bf16(d0.w, a0.w);
    v1[0] = cvt_pk_bf16(d1.x, a1.x); v1[1] = cvt_pk_bf16(d1.y, a1.y);
    v1[2] = cvt_pk_bf16(d1.z, a1.z); v1[3] = cvt_pk_bf16(d1.w, a1.w);
    *reinterpret_cast<int4v*>(&DAb[e]) = v0;
    *reinterpret_cast<int4v*>(&DAb[e + 4]) = v1;
    return;
  }
  int e = (bid * 256 + threadIdx.x) * 8;
  const float* src;
  int off;
  float qs = 1.0f;
  if (e < XE)                { src = x;  off = e; }
  else if (e < XE + WE)      { src = wq; off = e - XE; qs = QSCALE_L2E; }
  else if (e < XE + 2 * WE)  { src = wk; off = e - XE - WE; }
  else if (e < XE + 3 * WE)  { src = wv; off = e - XE - 2 * WE; }
  else                       { src = wo; off = e - XE - 3 * WE; }
  float4 f0 = *reinterpret_cast<const float4*>(&src[off]);
  float4 f1 = *reinterpret_cast<const float4*>(&src[off + 4]);
  int4v v;
  v[0] = cvt_pk_bf16(f0.x * qs, f0.y * qs);
  v[1] = cvt_pk_bf16(f0.z * qs, f0.w * qs);
  v[2] = cvt_pk_bf16(f1.x * qs, f1.y * qs);
  v[3] = cvt_pk_bf16(f1.z * qs, f1.w * qs);
  *reinterpret_cast<int4v*>(&dst[e]) = v;
}

// ---------------------------------------------------------------------------
// 2a) bf16 GEMM, 128x64 tile / WG (4 waves, each owning a 64x32 quadrant).
//     Used for the QKV projection (grid 24x32 = 768 WGs = 3/CU).
//     T1 XCD-aware block remap. XOR-swizzle invariant:
//     LDS[r][slot*8+j] holds global col-block (slot ^ (r&7)) of the k-tile;
//     fragment read at col 8*((blk) ^ (l15&7)).
// ---------------------------------------------------------------------------
template <bool F32OUT>
__global__ __launch_bounds__(256) void gemm_bt128x64(
    const ushort_t* __restrict__ A, const ushort_t* __restrict__ Bt,
    const float* __restrict__ bias, void* __restrict__ C,
    int N, int K) {
  __shared__ ushort_t As[128][64];
  __shared__ ushort_t Bs[64][64];
  const int tid  = threadIdx.x;
  const int wave = tid >> 6, lane = tid & 63;
  const int quad = lane >> 4, l15 = lane & 15;

  // T1 XCD-aware remap (grid sizes are multiples of 8)
  const int nb  = blockIdx.x + blockIdx.y * gridDim.x;
  const int tot = gridDim.x * gridDim.y;
  const int w   = (nb & 7) * (tot >> 3) + (nb >> 3);
  const int bx  = w % gridDim.x, by = w / gridDim.x;
  const int m0 = by * 128, n0 = bx * 64;
  const int wr = (wave >> 1) * 64, wc = (wave & 1) * 32;  // wave's C quadrant

  f32x4 acc[4][2] = {};

  // staging: A 128 rows (4 x async16/wave), B 64 rows (2 x async16/wave)
  const int lrow = lane >> 3, slot = lane & 7;
  const int cswz = 8 * (slot ^ lrow);
  const ushort_t* ag = A  + (size_t)(m0 + wave * 8 + lrow) * K + cswz;
  const ushort_t* bg = Bt + (size_t)(n0 + wave * 16 + lrow) * K + cswz;
  ushort_t* la[4];
#pragma unroll
  for (int r0 = 0; r0 < 4; r0++) la[r0] = &As[r0 * 32 + wave * 8][0];
  ushort_t* lb0 = &Bs[wave * 16][0];
  ushort_t* lb1 = &Bs[wave * 16 + 8][0];

  const int swz = l15 & 7;

  for (int k0 = 0; k0 < K; k0 += 64) {
    __syncthreads();
#pragma unroll
    for (int r0 = 0; r0 < 4; r0++)
      async16(ag + k0 + (size_t)(r0 * 32) * K, la[r0]);
    async16(bg + k0, lb0);
    async16(bg + k0 + 8 * (size_t)K, lb1);
    asm volatile("s_waitcnt vmcnt(0)" ::: "memory");
    __syncthreads();
#pragma unroll
    for (int s = 0; s < 2; s++) {
      const int acol = 8 * ((s * 4 + quad) ^ swz);
      bf16x8 af[4], bfr[2];
#pragma unroll
      for (int i = 0; i < 4; i++)
        af[i] = *reinterpret_cast<const bf16x8*>(&As[wr + i * 16 + l15][acol]);
#pragma unroll
      for (int j = 0; j < 2; j++)
        bfr[j] = *reinterpret_cast<const bf16x8*>(&Bs[wc + j * 16 + l15][acol]);
#pragma unroll
      for (int i = 0; i < 4; i++)
#pragma unroll
        for (int j = 0; j < 2; j++)
          acc[i][j] = MFMA16(af[i], bfr[j], acc[i][j]);
    }
  }

#pragma unroll
  for (int j = 0; j < 2; j++) {
    const int col = n0 + wc + j * 16 + l15;
    const float bv = bias[col];
#pragma unroll
    for (int i = 0; i < 4; i++) {
#pragma unroll
      for (int rr = 0; rr < 4; rr++) {
        const int row = m0 + wr + i * 16 + quad * 4 + rr;
        const float v = acc[i][j][rr] + bv;
        if (F32OUT) reinterpret_cast<float*>(C)[(size_t)row * N + col] = v;
        else        reinterpret_cast<ushort_t*>(C)[(size_t)row * N + col] = f2bf(v);
      }
    }
  }
}

// ---------------------------------------------------------------------------
// 2b) bf16 GEMM, 64x64 tile / WG (4 waves, each owning a 16-row stripe).
//     Used for the O-projection: grid (8, 64) = 512 WGs = 2 WG/CU.
//     Same XOR-swizzle invariant; T1 remap.
// ---------------------------------------------------------------------------
template <bool F32OUT>
__global__ __launch_bounds__(256) void gemm_bt64(
    const ushort_t* __restrict__ A, const ushort_t* __restrict__ Bt,
    const float* __restrict__ bias, void* __restrict__ C,
    int N, int K) {
  __shared__ ushort_t As[64][64];
  __shared__ ushort_t Bs[64][64];
  const int tid  = threadIdx.x;
  const int wave = tid >> 6, lane = tid & 63;
  const int quad = lane >> 4, l15 = lane & 15;

  // T1 XCD-aware remap (grid sizes are multiples of 8)
  const int nb  = blockIdx.x + blockIdx.y * gridDim.x;
  const int tot = gridDim.x * gridDim.y;
  const int w   = (nb & 7) * (tot >> 3) + (nb >> 3);
  const int bx  = w % gridDim.x, by = w / gridDim.x;
  const int m0 = by * 64, n0 = bx * 64;

  f32x4 acc[4] = {};

  const int lrow = lane >> 3, slot = lane & 7;
  const int cswz = 8 * (slot ^ lrow);
  const ushort_t* ag = A  + (size_t)(m0 + wave * 16 + lrow) * K + cswz;
  const ushort_t* bg = Bt + (size_t)(n0 + wave * 16 + lrow) * K + cswz;
  ushort_t* la0 = &As[wave * 16][0];
  ushort_t* la1 = &As[wave * 16 + 8][0];
  ushort_t* lb0 = &Bs[wave * 16][0];
  ushort_t* lb1 = &Bs[wave * 16 + 8][0];

  const int swz = l15 & 7;

  for (int k0 = 0; k0 < K; k0 += 64) {
    __syncthreads();
    async16(ag + k0, la0);
    async16(ag + k0 + 8 * (size_t)K, la1);
    async16(bg + k0, lb0);
    async16(bg + k0 + 8 * (size_t)K, lb1);
    asm volatile("s_waitcnt vmcnt(0)" ::: "memory");
    __syncthreads();
#pragma unroll
    for (int s = 0; s < 2; s++) {
      const int acol = 8 * ((s * 4 + quad) ^ swz);
      bf16x8 af = *reinterpret_cast<const bf16x8*>(&As[wave * 16 + l15][acol]);
#pragma unroll
      for (int t = 0; t < 4; t++) {
        bf16x8 bfr = *reinterpret_cast<const bf16x8*>(&Bs[t * 16 + l15][acol]);
        acc[t] = MFMA16(af, bfr, acc[t]);
      }
    }
  }

#pragma unroll
  for (int t = 0; t < 4; t++) {
    const int col = n0 + t * 16 + l15;
    const float bv = bias[col];
#pragma unroll
    for (int rr = 0; rr < 4; rr++) {
      const int row = m0 + wave * 16 + quad * 4 + rr;
      const float v = acc[t][rr] + bv;
      if (F32OUT) reinterpret_cast<float*>(C)[(size_t)row * N + col] = v;
      else        reinterpret_cast<ushort_t*>(C)[(size_t)row * N + col] = f2bf(v);
    }
  }
}

// ---------------------------------------------------------------------------
// 3) Fused flash attention (R7-proven config: 256 thr, QBLK=64, packed DA,
//    NSPLIT=4 -> 2048 WGs; TLP dominates split-K write savings, per R8).
//    T1 XCD-aware work remap (h decoded fastest within each XCD chunk) +
//    T5 s_setprio(1) around the QK^T and PV MFMA clusters.
//    Q pre-scaled by 0.125*log2e -> log2-domain softmax. P/V use k'-permuted
//    contraction order (k' = 4*(k&15)+(k>>4)).
// ---------------------------------------------------------------------------
__global__ __launch_bounds__(256) void attn_kernel(
    const ushort_t* __restrict__ QKV, const uint_t* __restrict__ DA,
    const float* __restrict__ wd, const float* __restrict__ wa,
    float* __restrict__ Opart, float* __restrict__ Mp, float* __restrict__ Lp) {
  // T1: flat id over (32, 8, 8) grid; w = (n%8)*256 + n/8; decode h fastest.
  const int n = blockIdx.x + (blockIdx.y << 5) + (blockIdx.z << 8);  // 0..2047
  const int w = ((n & 7) << 8) | (n >> 3);
  const int h = w & 7;
  const int qb = (w >> 3) & 31;
  const int z = w >> 8;                      // 0..7
  const int b = z >> 2, split = z & 3;       // NSPLIT = 4
  const int tid = threadIdx.x;
  const int wave = tid >> 6, lane = tid & 63;
  const int quad = lane >> 4, l15 = lane & 15;
  const int q0 = qb * 64;
  const float wdh = wd[h] * L2E, wah = wa[h] * L2E;

  __shared__ ushort_t Ks[64][64];                 // K tile, XOR-swizzled col blocks
  __shared__ ushort_t Vts[64][64];                // V^T tile (k'-order), XOR-swizzled
  __shared__ __align__(16) ushort_t Ps[4][16][72]; // P (k'-order), +8 pad

  // Q fragments for this wave's 16-query stripe
  const int qrow = q0 + wave * 16 + l15;
  bf16x8 qf[2];
#pragma unroll
  for (int s = 0; s < 2; s++)
    qf[s] = *reinterpret_cast<const bf16x8*>(
        &QKV[(size_t)(b * SEQ + qrow) * NQKV + h * DK + s * 32 + quad * 8]);

  bf16x8 ones;
#pragma unroll
  for (int j = 0; j < 8; j++) ones[j] = (short)0x3F80;  // bf16 1.0

  float m_run[4], l_run[4];
  f32x4 o[4] = {};
#pragma unroll
  for (int rr = 0; rr < 4; rr++) { m_run[rr] = -INFINITY; l_run[rr] = 0.f; }

  // K staging (async): per wave 16 rows, 2 insts
  const int lrow = lane >> 3, slot = lane & 7;
  const ushort_t* kg = QKV + (size_t)(b * SEQ + wave * 16 + lrow) * NQKV +
                       512 + h * DK + 8 * (slot ^ lrow);
  ushort_t* lk0 = &Ks[wave * 16][0];
  ushort_t* lk1 = &Ks[wave * 16 + 8][0];

  // V staging (manual transpose into k'-order; k'(kv) == u, k'(kv+8) == u+32)
  const int u  = tid >> 3;                    // 0..31
  const int c7 = tid & 7;
  const int sc = c7 * 8;                      // d-offset this thread handles
  const int kv = ((u & 3) << 4) | (u >> 2);   // logical k row this thread loads
  const ushort_t* vg = QKV + (size_t)(b * SEQ + kv) * NQKV + 1024 + h * DK + sc;
  const int col0 = (u & 7) + 8 * ((u >> 3) ^ c7);
  const int col1 = (u & 7) + 8 * (((u >> 3) + 4) ^ c7);

  const int swz = l15 & 7;
  const uint_t* DArow = DA + (size_t)b * SEQ * SEQ;

  for (int kbi = 0; kbi < KB_PER; kbi++) {
    const int k0 = (split * KB_PER + kbi) * 64;
    __syncthreads();
    async16(kg + (size_t)k0 * NQKV, lk0);
    async16(kg + (size_t)(k0 + 8) * NQKV, lk1);
    bf16x8 v0 = *reinterpret_cast<const bf16x8*>(vg + (size_t)k0 * NQKV);
    bf16x8 v1 = *reinterpret_cast<const bf16x8*>(vg + (size_t)(k0 + 8) * NQKV);
#pragma unroll
    for (int j = 0; j < 8; j++) {
      Vts[sc + j][col0] = (ushort_t)v0[j];
      Vts[sc + j][col1] = (ushort_t)v1[j];
    }

    // issue bias loads now: they drain under the same vmcnt(0) as staging
    uint_t da[4][4];
#pragma unroll
    for (int t = 0; t < 4; t++) {
      const int kk = k0 + t * 16 + l15;
#pragma unroll
      for (int rr = 0; rr < 4; rr++) {
        const int qg = q0 + wave * 16 + quad * 4 + rr;
        da[t][rr] = DArow[(size_t)qg * SEQ + kk];
      }
    }

    asm volatile("s_waitcnt vmcnt(0)" ::: "memory");
    __syncthreads();

    // S(log2) = Q'K^T + wd'*D + wa'*A   (Q pre-scaled by 0.125*log2e)
    f32x4 sacc[4];
    __builtin_amdgcn_s_setprio(1);
#pragma unroll
    for (int t = 0; t < 4; t++) {
      bf16x8 kf0 = *reinterpret_cast<const bf16x8*>(&Ks[t * 16 + l15][8 * (quad ^ swz)]);
      bf16x8 kf1 = *reinterpret_cast<const bf16x8*>(&Ks[t * 16 + l15][8 * ((4 + quad) ^ swz)]);
      f32x4 z2 = {};
      z2 = MFMA16(qf[0], kf0, z2);
      sacc[t] = MFMA16(qf[1], kf1, z2);
    }
    __builtin_amdgcn_s_setprio(0);

    float sv[4][4];
    float mx[4] = {-INFINITY, -INFINITY, -INFINITY, -INFINITY};
#pragma unroll
    for (int t = 0; t < 4; t++) {
#pragma unroll
      for (int rr = 0; rr < 4; rr++) {
        const float fd = __builtin_bit_cast(float, da[t][rr] << 16);
        const float fa = __builtin_bit_cast(float, da[t][rr] & 0xFFFF0000u);
        float s = fmaf(wdh, fd, fmaf(wah, fa, sacc[t][rr]));
        sv[t][rr] = s;
        mx[rr] = fmaxf(mx[rr], s);
      }
    }
    // row max via DPP (lanes 0-15 of each quad-group == one DPP row)
#pragma unroll
    for (int rr = 0; rr < 4; rr++) mx[rr] = rowmax16(mx[rr]);

    // defer-max: only rescale when some row max grew by > ~8 nats (11.5 bits)
    bool grow = false;
#pragma unroll
    for (int rr = 0; rr < 4; rr++) grow |= (mx[rr] > m_run[rr] + 11.5f);
    if (__ballot(grow)) {
      float alpha[4];
#pragma unroll
      for (int rr = 0; rr < 4; rr++) {
        const float mn = fmaxf(m_run[rr], mx[rr]);
        alpha[rr] = fexp2(m_run[rr] - mn);
        m_run[rr] = mn;
        l_run[rr] *= alpha[rr];
      }
#pragma unroll
      for (int dt = 0; dt < 4; dt++)
#pragma unroll
        for (int rr = 0; rr < 4; rr++) o[dt][rr] *= alpha[rr];
    }

    // P = 2^(S - m), packed 2x bf16 per dword, 4 contiguous k' per b64 write
#pragma unroll
    for (int rr = 0; rr < 4; rr++) {
      const float m = m_run[rr];
      i32x2 wv2;
      wv2[0] = cvt_pk_bf16(fexp2(sv[0][rr] - m), fexp2(sv[1][rr] - m));
      wv2[1] = cvt_pk_bf16(fexp2(sv[2][rr] - m), fexp2(sv[3][rr] - m));
      *reinterpret_cast<i32x2*>(&Ps[wave][quad * 4 + rr][l15 * 4]) = wv2;
    }

    // Ps is wave-private: wave-local LDS drain is enough (no barrier)
    asm volatile("s_waitcnt lgkmcnt(0)" ::: "memory");

    // O += P @ V ; row-sum(P) via MFMA with all-ones B operand
    f32x4 rsacc = {};
    __builtin_amdgcn_s_setprio(1);
#pragma unroll
    for (int s2 = 0; s2 < 2; s2++) {
      bf16x8 pf = *reinterpret_cast<const bf16x8*>(&Ps[wave][l15][s2 * 32 + quad * 8]);
#pragma unroll
      for (int dt = 0; dt < 4; dt++) {
        const int vrow = dt * 16 + l15;
        const int vcb = (s2 * 4 + quad) ^ (vrow >> 3);
        bf16x8 vf = *reinterpret_cast<const bf16x8*>(&Vts[vrow][vcb * 8]);
        o[dt] = MFMA16(pf, vf, o[dt]);
      }
      rsacc = MFMA16(pf, ones, rsacc);
    }
    __builtin_amdgcn_s_setprio(0);
#pragma unroll
    for (int rr = 0; rr < 4; rr++) l_run[rr] += rsacc[rr];
  }

  // epilogue: write fp32 partials (un-normalized) + m, l
  const int pidx = (((b * NHEADS + h) * 32 + qb) * NSPLIT + split);
  float* op = Opart + (size_t)pidx * 4096;
#pragma unroll
  for (int dt = 0; dt < 4; dt++) {
#pragma unroll
    for (int rr = 0; rr < 4; rr++) {
      const int row = wave * 16 + quad * 4 + rr;
      op[row * 64 + dt * 16 + l15] = o[dt][rr];
    }
  }
  if (l15 == 0) {
#pragma unroll
    for (int rr = 0; rr < 4; rr++) {
      const int row = wave * 16 + quad * 4 + rr;
      Mp[(size_t)pidx * 64 + row] = m_run[rr];
      Lp[(size_t)pidx * 64 + row] = l_run[rr];
    }
  }
}

// ---------------------------------------------------------------------------
// 3b) split-K combine (m is in log2 domain -> exp2). Grid z = BATCH*4:
//     each block handles a 4-row chunk (rs) of its q-block -> 2048 WGs.
// ---------------------------------------------------------------------------
__global__ __launch_bounds__(256) void combine_kernel(
    const float* __restrict__ Opart, const float* __restrict__ Mp,
    const float* __restrict__ Lp, ushort_t* __restrict__ AO) {
  const int qb = blockIdx.x, h = blockIdx.y;
  const int b = blockIdx.z >> 2, rs = blockIdx.z & 3;
  const int tid = threadIdx.x;
  const int lane = tid & 63, wq = tid >> 6;
  const int pidx0 = ((b * NHEADS + h) * 32 + qb) * NSPLIT;

  for (int r = rs * 4; r < rs * 4 + 4; r++) {
    const int q = wq * 16 + r;
    float m[NSPLIT], l[NSPLIT];
    float M = -INFINITY;
#pragma unroll
    for (int s = 0; s < NSPLIT; s++) {
      m[s] = Mp[(size_t)(pidx0 + s) * 64 + q];
      l[s] = Lp[(size_t)(pidx0 + s) * 64 + q];
      M = fmaxf(M, m[s]);
    }
    float L = 0.f, acc = 0.f;
#pragma unroll
    for (int s = 0; s < NSPLIT; s++) {
      const float w = fexp2(m[s] - M);
      L += l[s] * w;
      acc += Opart[(size_t)(pidx0 + s) * 4096 + q * 64 + lane] * w;
    }
    const int row = b * SEQ + qb * 64 + q;
    AO[(size_t)row * DMODEL + h * DK + lane] = f2bf(acc / L);
  }
}

// ---------------------------------------------------------------------------
extern "C" void kernel_launch(void* const* d_in, const int* in_sizes, int n_in,
                              void* d_out, int out_size, void* d_ws, size_t ws_size,
                              hipStream_t stream) {
  const float* x  = (const float*)d_in[0];
  const float* Dm = (const float*)d_in[1];
  const float* Am = (const float*)d_in[2];
  const float* Wq = (const float*)d_in[3];
  const float* bq = (const float*)d_in[4];
  const float* Wk = (const float*)d_in[5];
  const float* bk = (const float*)d_in[6];
  const float* Wv = (const float*)d_in[7];
  const float* bv = (const float*)d_in[8];
  const float* Wo = (const float*)d_in[9];
  const float* bo = (const float*)d_in[10];
  const float* wd = (const float*)d_in[11];
  const float* wa = (const float*)d_in[12];

  char* ws = (char*)d_ws;
  size_t off = 0;
  ushort_t* xb    = (ushort_t*)(ws + off); off += (size_t)XE * 2;         // 4 MB
  ushort_t* wqkvb = (ushort_t*)(ws + off); off += (size_t)3 * WE * 2;     // 1.5 MB
  ushort_t* wob   = (ushort_t*)(ws + off); off += (size_t)WE * 2;         // 0.5 MB
  ushort_t* QKVb  = (ushort_t*)(ws + off); off += (size_t)MROWS * NQKV * 2; // 12 MB
  ushort_t* AO    = (ushort_t*)(ws + off); off += (size_t)XE * 2;         // 4 MB
  float*    bqkv  = (float*)(ws + off);    off += (size_t)NQKV * 4;       // 6 KB
  off = (off + 255) & ~(size_t)255;
  uint_t*   DAb   = (uint_t*)(ws + off);   off += (size_t)BATCH * SEQ * SEQ * 4; // 33.5 MB
  float*    Opart = (float*)(ws + off);    off += (size_t)512 * NSPLIT * 4096 * 4; // 33.5 MB
  float*    Mpart = (float*)(ws + off);    off += (size_t)512 * NSPLIT * 64 * 4;
  float*    Lpart = (float*)(ws + off);

  // 1) fused prep: convert to bf16 (+bias concat, Wq/bq pre-scaled) + D/A pack
  convert_pack_kernel<<<CONV_BLOCKS + 1 + PACK_BLOCKS, 256, 0, stream>>>(
      x, Wq, Wk, Wv, Wo, bq, bk, bv, Dm, Am, xb, bqkv, DAb);

  // 2) fused QKV projection: (4096 x 512) @ (1536 x 512)^T, 128x64 tiles
  dim3 qkvgrid(NQKV / 64, MROWS / 128);
  gemm_bt128x64<false><<<qkvgrid, 256, 0, stream>>>(xb, wqkvb, bqkv, QKVb, NQKV, DMODEL);

  // 3) fused attention (split-K=4, packed DA, XCD remap + setprio) + combine
  dim3 agrid(SEQ / 64, NHEADS, BATCH * NSPLIT);
  attn_kernel<<<agrid, 256, 0, stream>>>(QKVb, DAb, wd, wa, Opart, Mpart, Lpart);
  dim3 cgrid(SEQ / 64, NHEADS, BATCH * 4);
  combine_kernel<<<cgrid, 256, 0, stream>>>(Opart, Mpart, Lpart, AO);

  // 4) output projection (fp32 out), 64x64 tiles (512 WGs = 2/CU)
  dim3 ogrid(DMODEL / 64, MROWS / 64);
  gemm_bt64<true><<<ogrid, 256, 0, stream>>>(AO, wob, bo, (float*)d_out, DMODEL, DMODEL);
}